// Round 5
// baseline (50900.644 us; speedup 1.0000x reference)
//
#include <hip/hip_runtime.h>
#include <hip/hip_cooperative_groups.h>
#include <hip/hip_bf16.h>
#include <cstddef>

typedef unsigned short u16;
typedef unsigned long long u64t;
typedef __attribute__((ext_vector_type(8))) short s8;   // 8 bf16 = 4 VGPRs
typedef __attribute__((ext_vector_type(4))) float f4;   // MFMA acc

constexpr int kB = 64, kT = 256, kD = 128, kH = 1024, kL = 5, kC = 10, kG = 4096;
constexpr int BH = kB * kH;
constexpr size_t WLAQ_BYTES = (size_t)256 * 8 * 16384;  // 33.5 MB int8 lo (task A)
constexpr size_t WLBQ_BYTES = (size_t)256 * 8 * 2560;   // 5.2 MB int8 lo (task B)
constexpr size_t H2_ELEMS = (size_t)kL * kT * BH;       // unique h buffer per (l,t)

// h activations: FRAGMENT-CONTIGUOUS H2[k>>3][b][k&7] (u16); unique buffer per
// (layer,timestep) => readers are first-touch, plain cached loads (R3).
//
// THIS REVISION: the recurring lo-weight STREAM is eliminated. In every round
// dur tracked TCC-fetch-bytes / ~1.3 TB/s, and the dominant byte term was the
// 60 MB/step block-private wl stream (zero reuse). The hi-weights already fill
// half the register file (128 AGPR x 8 waves = 256 of 512 KB/CU), and bf16-lo
// (77 MB) exceeds aggregate LDS — but lo needs only 8 BITS when encoded in
// units of its hi's ULP:  q = round((w-hi)*2^(15-E_hi)) in [-127,127],
// reconstruction lo = q*2^(E_hi-16). Quantization step 2^(E_hi-16) ==
// bf16-lo's error bound, so precision is unchanged. As int8 the per-block
// wlA-lo is 128 KB -> parked ENTIRELY in LDS (157,696 B total, same as
// before). Decode at use: ~8 VALU/elem against hi bits already in registers;
// q*2^sb fits bf16 exactly (trunc f32->bf16 is exact). wlB-lo is int8 too
// (40 B/lane global, L2-hot). DMA ring / manual vmcnt / sched_barriers:
// deleted. Per-step fetched bytes collapse to h-fills + x only.

__device__ __forceinline__ float sigf(float x) { return 1.f / (1.f + __expf(-x)); }
__device__ __forceinline__ float tanh_s(float x) {
  float ax = fabsf(x);
  float e = __expf(-2.f * ax);
  float r = (1.f - e) / (1.f + e);
  return copysignf(r, x);
}
__device__ __forceinline__ void split_bf16(float v, short& hi, short& lo) {
  __hip_bfloat16 h = __float2bfloat16(v);
  hi = __builtin_bit_cast(short, h);
  float fh = __bfloat162float(h);
  __hip_bfloat16 l = __float2bfloat16(v - fh);
  lo = __builtin_bit_cast(short, l);
}
__device__ __forceinline__ float bf2f(u16 v) {
  unsigned u = ((unsigned)v) << 16;
  return __builtin_bit_cast(float, u);
}

// ---- weight hi: manual RNE f32->bf16 (must be bit-identical in prep+main) ----
__device__ __forceinline__ unsigned rne16(float w) {
  unsigned wb = __builtin_bit_cast(unsigned, w);
  return (wb + 0x7FFFu + ((wb >> 16) & 1u)) & 0xFFFF0000u;
}
__device__ __forceinline__ short hi_rne(float w) {
  return (short)(rne16(w) >> 16);
}
// encode: hi (bits) + int8 residual in hi-ULP units
__device__ __forceinline__ char enc_q(float w) {
  unsigned r16 = rne16(w);
  float fh = __builtin_bit_cast(float, r16);
  float r = w - fh;
  int e = (int)((r16 >> 23) & 0xFF);
  int qi = 0;
  if (e >= 16) {
    float inv = __builtin_bit_cast(float, (unsigned)(269 - e) << 23);  // 2^(15-E)
    qi = __float2int_rn(r * inv);
    qi = qi > 127 ? 127 : (qi < -127 ? -127 : qi);
  }
  return (char)qi;
}
// decode 8 packed int8 -> 8 bf16 lo, given matching hi fragment
__device__ __forceinline__ s8 dec_lo(u64t qp, s8 hi) {
  s8 lo;
  const unsigned qa = (unsigned)qp, qb = (unsigned)(qp >> 32);
#pragma unroll
  for (int j = 0; j < 8; ++j) {
    unsigned src = (j < 4) ? qa : qb;
    int q = ((int)(src << ((3 - (j & 3)) * 8))) >> 24;   // sign-extended byte
    int e = ((int)(unsigned short)hi[j] >> 7) & 0xFF;    // hi biased exponent
    int sb = e - 15;
    sb = sb < 0 ? 0 : sb;
    float scale = __builtin_bit_cast(float, (unsigned)sb << 23);  // 2^(E-15)
    float lf = (float)q * scale;                                   // exact
    lo[j] = (short)(__builtin_bit_cast(unsigned, lf) >> 16);       // exact trunc
  }
  return lo;
}

__device__ __forceinline__ void sth8(u16* p, u64t v) {
  __hip_atomic_store((u64t*)p, v, __ATOMIC_RELAXED, __HIP_MEMORY_SCOPE_AGENT);
}
__device__ __forceinline__ unsigned aload(const unsigned* p) {
  return __hip_atomic_load(p, __ATOMIC_RELAXED, __HIP_MEMORY_SCOPE_AGENT);
}
__device__ __forceinline__ void dma16(const void* gsrc, void* ldst) {
  __builtin_amdgcn_global_load_lds(
      (const __attribute__((address_space(1))) void*)gsrc,
      (__attribute__((address_space(3))) void*)ldst, 16, 0, 0);
}

// ---- prep: int8-encode lo-weights in per-(block,wave) fragment order ----
__global__ void __launch_bounds__(512) split_wl(const float* __restrict__ Wx0,
                                                const float* __restrict__ Wxs,
                                                const float* __restrict__ Whs,
                                                char* __restrict__ wlAq,
                                                char* __restrict__ wlBq,
                                                unsigned* __restrict__ bar) {
  const int g = blockIdx.x, tid = threadIdx.x;
  const int wv = tid >> 6, lane = tid & 63, quad = lane >> 4, r = lane & 15;
  const int lA = (g >> 6) + 1, jb = g & 63, kq = wv & 3, ch = wv >> 2;
  const float* WxA = Wxs + (size_t)(lA - 1) * kH * kG;
  const float* WhA = Whs + (size_t)lA * kH * kG;

  if (g == 0)
    for (int i = tid; i < 4096; i += 512) bar[i] = 0;

  char* dA = wlAq + (size_t)(g * 8 + wv) * 16384;
  for (int p = 0; p < 16; ++p) {
    int kc = 4 * p + kq;
    const float* W = (kc < 32) ? WxA : WhA;
    int krow0 = (kc & 31) * 32 + quad * 8;
    for (int ntl = 0; ntl < 2; ++ntl) {
      int col = (2 * ch + ntl) * kH + jb * 16 + r;
      u64t qw = 0;
      for (int j = 0; j < 8; ++j) {
        char q = enc_q(W[(size_t)(krow0 + j) * kG + col]);
        qw |= ((u64t)(unsigned char)q) << (8 * j);
      }
      *(u64t*)(dA + (size_t)((p * 2 + ntl) * 64 + lane) * 8) = qw;
    }
  }

  char* dB = wlBq + (size_t)(g * 8 + wv) * 2560;
  int colB = (r >> 2) * kH + g * 4 + (r & 3);
  for (int j2 = 0; j2 < 4; ++j2) {
    int kb = (wv & 3) + 4 * (2 * j2 + (wv >> 2));
    int krow0 = kb * 32 + quad * 8;
    u64t qw = 0;
    for (int j = 0; j < 8; ++j) {
      char q = enc_q(Whs[(size_t)(krow0 + j) * kG + colB]);
      qw |= ((u64t)(unsigned char)q) << (8 * j);
    }
    *(u64t*)(dB + (size_t)(j2 * 64 + lane) * 8) = qw;
  }
  {
    int krow0 = (wv & 3) * 32 + quad * 8;
    u64t qw = 0;
    for (int j = 0; j < 8; ++j) {
      char q = enc_q(Wx0[(size_t)(krow0 + j) * kG + colB]);
      qw |= ((u64t)(unsigned char)q) << (8 * j);
    }
    *(u64t*)(dB + (size_t)(4 * 64 + lane) * 8) = qw;
  }
}

// ---- main persistent kernel ----
__global__ void __launch_bounds__(512, 2) lstm_persist(
    const float* __restrict__ x, const float* __restrict__ Wx0,
    const float* __restrict__ Wxs, const float* __restrict__ Whs,
    const float* __restrict__ bs, const float* __restrict__ W_head,
    const float* __restrict__ b_head, float* __restrict__ out,
    u16* __restrict__ hhi, u16* __restrict__ hlo,
    const char* __restrict__ wlAq, const char* __restrict__ wlBq,
    unsigned* __restrict__ bar) {
  __shared__ char wq[8][16384];      // 128 KB: ALL wlA-lo int8, parked
  __shared__ float zA[64 * 66];
  __shared__ float zB[64 * 18];
  __shared__ u16 hstA[2][128][8];    // 4 KB
  __shared__ u16 hstB[2][64][4];     // 1 KB

  const int tid = threadIdx.x;
  const int wv = tid >> 6, lane = tid & 63, quad = lane >> 4, r = lane & 15;
  const int ch = wv >> 2, kq = wv & 3;
  const int g = blockIdx.x;
  const int lA = (g >> 6) + 1;
  const int jb = g & 63;
  const int ub = g * 4;

  const float* __restrict__ WxA = Wxs + (size_t)(lA - 1) * kH * kG;
  const float* __restrict__ WhA = Whs + (size_t)lA * kH * kG;

  // ---- one-time: park wlA-lo int8 into LDS (async DMA, 16 KB/wave) ----
  {
    const char* qsrc = wlAq + (size_t)(g * 8 + wv) * 16384;
#pragma unroll
    for (int i = 0; i < 16; ++i)
      dma16(qsrc + (size_t)i * 1024 + (size_t)lane * 16, &wq[wv][i * 1024]);
  }

  // ---- one-time: HI weight fragments into registers (AGPR-backed) ----
  s8 wA[16][2];  // 128 regs
#pragma unroll
  for (int p = 0; p < 16; ++p) {
    int kc = 4 * p + kq;
    const float* W = (kc < 32) ? WxA : WhA;
    int krow0 = (kc & 31) * 32 + quad * 8;
#pragma unroll
    for (int ntl = 0; ntl < 2; ++ntl) {
      int col = (2 * ch + ntl) * kH + jb * 16 + r;
      s8 h8;
#pragma unroll
      for (int j = 0; j < 8; ++j) h8[j] = hi_rne(W[(size_t)(krow0 + j) * kG + col]);
      wA[p][ntl] = h8;
    }
  }
  s8 wBh[4], wBx;
  {
    int colB = (r >> 2) * kH + ub + (r & 3);
#pragma unroll
    for (int j2 = 0; j2 < 4; ++j2) {
      int kb = (wv & 3) + 4 * (2 * j2 + (wv >> 2));
      int krow0 = kb * 32 + quad * 8;
      s8 h8;
#pragma unroll
      for (int j = 0; j < 8; ++j) h8[j] = hi_rne(Whs[(size_t)(krow0 + j) * kG + colB]);
      wBh[j2] = h8;
    }
    int krow0 = (wv & 3) * 32 + quad * 8;
    s8 h8;
#pragma unroll
    for (int j = 0; j < 8; ++j) h8[j] = hi_rne(Wx0[(size_t)(krow0 + j) * kG + colB]);
    wBx = h8;
  }

  const char* wlBs = wlBq + (size_t)(g * 8 + wv) * 2560;

  float bA[4], bB[4];
  {
    int u = tid & 15;
#pragma unroll
    for (int g4 = 0; g4 < 4; ++g4) bA[g4] = bs[(size_t)lA * kG + g4 * kH + jb * 16 + u];
    int u2 = tid & 3;
#pragma unroll
    for (int g4 = 0; g4 < 4; ++g4) bB[g4] = bs[(size_t)g4 * kH + ub + u2];
  }
  float cA0 = 0.f, cA1 = 0.f, cB0 = 0.f;
  const s8 zf = {0, 0, 0, 0, 0, 0, 0, 0};
  const f4 zero4 = {0.f, 0.f, 0.f, 0.f};
  const int fragbase = kq * 4 + quad;  // kk8 offset within a 16-group (128 k)

  __syncthreads();

  // ---- wavefront loop ----
  for (int s = 0; s < kT + kL - 1; ++s) {
    const int tA = s - lA;
    const int tB = s;

    for (int i = tid; i < 64 * 66; i += 512) zA[i] = 0.f;
    for (int i = tid; i < 64 * 18; i += 512) zB[i] = 0.f;
    __syncthreads();

    // ---- task A: weights all resident (hi regs, lo int8 LDS) ----
    if (tA >= 0 && tA < kT) {
      const int tAm1 = (tA > 0) ? tA - 1 : 0;
      const u16* IH = hhi + ((size_t)(lA - 1) * kT + tA) * BH;
      const u16* IL = hlo + ((size_t)(lA - 1) * kT + tA) * BH;
      const u16* RH = hhi + ((size_t)lA * kT + tAm1) * BH;
      const u16* RL = hlo + ((size_t)lA * kT + tAm1) * BH;
      const bool zz = (tA == 0);
      f4 accA[2][4];
#pragma unroll
      for (int a = 0; a < 2; ++a)
#pragma unroll
        for (int b = 0; b < 4; ++b) accA[a][b] = zero4;

      s8 ah_n[4];
#pragma unroll
      for (int mt = 0; mt < 4; ++mt)
        ah_n[mt] = *(const s8*)(IH + (size_t)(fragbase * 64 + mt * 16 + r) * 8);

#pragma unroll
      for (int p = 0; p < 16; ++p) {
        const bool curR = (p >= 8);
        // al for CURRENT p at iter top, consumed LAST (latency hidden by
        // 16 MFMAs + decode).
        const u16* SL = curR ? RL : IL;
        const int kb8c = ((p & 7) * 16 + fragbase) * 64;
        s8 al_c[4];
#pragma unroll
        for (int mt = 0; mt < 4; ++mt)
          al_c[mt] = *(const s8*)(SL + (size_t)(kb8c + mt * 16 + r) * 8);
        // lo int8 from LDS + decode against resident hi
        u64t q0 = *(const u64t*)&wq[wv][(size_t)((p * 2 + 0) * 64 + lane) * 8];
        u64t q1 = *(const u64t*)&wq[wv][(size_t)((p * 2 + 1) * 64 + lane) * 8];
        s8 ah_c[4];
#pragma unroll
        for (int mt = 0; mt < 4; ++mt) ah_c[mt] = (curR && zz) ? zf : ah_n[mt];
        s8 wl0 = dec_lo(q0, wA[p][0]);
        s8 wl1 = dec_lo(q1, wA[p][1]);
        // ah x hi
#pragma unroll
        for (int mt = 0; mt < 4; ++mt) {
          accA[0][mt] =
              __builtin_amdgcn_mfma_f32_16x16x32_bf16(ah_c[mt], wA[p][0], accA[0][mt], 0, 0, 0);
          accA[1][mt] =
              __builtin_amdgcn_mfma_f32_16x16x32_bf16(ah_c[mt], wA[p][1], accA[1][mt], 0, 0, 0);
        }
        // prefetch next ah
        if (p < 15) {
          const int pn = p + 1;
          const u16* SH = (pn >= 8) ? RH : IH;
          const int kb8n = ((pn & 7) * 16 + fragbase) * 64;
#pragma unroll
          for (int mt = 0; mt < 4; ++mt)
            ah_n[mt] = *(const s8*)(SH + (size_t)(kb8n + mt * 16 + r) * 8);
        }
        // ah x lo
#pragma unroll
        for (int mt = 0; mt < 4; ++mt) {
          accA[0][mt] =
              __builtin_amdgcn_mfma_f32_16x16x32_bf16(ah_c[mt], wl0, accA[0][mt], 0, 0, 0);
          accA[1][mt] =
              __builtin_amdgcn_mfma_f32_16x16x32_bf16(ah_c[mt], wl1, accA[1][mt], 0, 0, 0);
        }
        // al x hi (compiler waits al here)
        s8 alz[4];
#pragma unroll
        for (int mt = 0; mt < 4; ++mt) alz[mt] = (curR && zz) ? zf : al_c[mt];
#pragma unroll
        for (int mt = 0; mt < 4; ++mt) {
          accA[0][mt] =
              __builtin_amdgcn_mfma_f32_16x16x32_bf16(alz[mt], wA[p][0], accA[0][mt], 0, 0, 0);
          accA[1][mt] =
              __builtin_amdgcn_mfma_f32_16x16x32_bf16(alz[mt], wA[p][1], accA[1][mt], 0, 0, 0);
        }
      }
#pragma unroll
      for (int ntl = 0; ntl < 2; ++ntl)
#pragma unroll
        for (int mt = 0; mt < 4; ++mt)
#pragma unroll
          for (int v = 0; v < 4; ++v)
            atomicAdd(&zA[(mt * 16 + quad * 4 + v) * 66 + (2 * ch + ntl) * 16 + r],
                      accA[ntl][mt][v]);
    }

    // ---- task B: 4 units of layer 0 ----
    if (tB < kT) {
      const int tBm1 = (tB > 0) ? tB - 1 : 0;
      const u16* H0H = hhi + (size_t)tBm1 * BH;
      const u16* H0L = hlo + (size_t)tBm1 * BH;
      const bool z0 = (tB == 0);
      f4 accB[4];
#pragma unroll
      for (int b = 0; b < 4; ++b) accB[b] = zero4;

      s8 ahb_n[4];
      {
        const int kb0 = (wv & 3) + 4 * (wv >> 2);
        const int kb8 = (kb0 * 4 + quad) * 64;
#pragma unroll
        for (int mt = 0; mt < 4; ++mt)
          ahb_n[mt] = *(const s8*)(H0H + (size_t)(kb8 + mt * 16 + r) * 8);
      }
#pragma unroll
      for (int j2 = 0; j2 < 4; ++j2) {
        const int kb = (wv & 3) + 4 * (2 * j2 + (wv >> 2));
        const int kb8c = (kb * 4 + quad) * 64;
        u64t qb = *(const u64t*)(wlBs + (size_t)(j2 * 64 + lane) * 8);
        s8 wlv = dec_lo(qb, wBh[j2]);
        s8 ahb_c[4];
#pragma unroll
        for (int mt = 0; mt < 4; ++mt) ahb_c[mt] = z0 ? zf : ahb_n[mt];
        if (j2 < 3) {
          const int kbn = (wv & 3) + 4 * (2 * (j2 + 1) + (wv >> 2));
          const int kb8n = (kbn * 4 + quad) * 64;
#pragma unroll
          for (int mt = 0; mt < 4; ++mt)
            ahb_n[mt] = *(const s8*)(H0H + (size_t)(kb8n + mt * 16 + r) * 8);
        }
        s8 alb[4];
#pragma unroll
        for (int mt = 0; mt < 4; ++mt) {
          s8 v = *(const s8*)(H0L + (size_t)(kb8c + mt * 16 + r) * 8);
          alb[mt] = z0 ? zf : v;
        }
#pragma unroll
        for (int mt = 0; mt < 4; ++mt) {
          f4 a = accB[mt];
          a = __builtin_amdgcn_mfma_f32_16x16x32_bf16(ahb_c[mt], wBh[j2], a, 0, 0, 0);
          a = __builtin_amdgcn_mfma_f32_16x16x32_bf16(alb[mt], wBh[j2], a, 0, 0, 0);
          a = __builtin_amdgcn_mfma_f32_16x16x32_bf16(ahb_c[mt], wlv, a, 0, 0, 0);
          accB[mt] = a;
        }
      }
      if (wv >= 4) {
        const int c = wv - 4;
        u64t qx = *(const u64t*)(wlBs + (size_t)(4 * 64 + lane) * 8);
        s8 wlx = dec_lo(qx, wBx);
#pragma unroll
        for (int mt = 0; mt < 4; ++mt) {
          const float* sx =
              x + (size_t)(mt * 16 + r) * kT * kD + (size_t)tB * kD + c * 32 + quad * 8;
          float4 v0 = *(const float4*)sx;
          float4 v1 = *(const float4*)(sx + 4);
          float vv[8] = {v0.x, v0.y, v0.z, v0.w, v1.x, v1.y, v1.z, v1.w};
          s8 xh, xl;
#pragma unroll
          for (int e = 0; e < 8; ++e) {
            short hh, ll;
            split_bf16(vv[e], hh, ll);
            xh[e] = hh;
            xl[e] = ll;
          }
          f4 a = accB[mt];
          a = __builtin_amdgcn_mfma_f32_16x16x32_bf16(xh, wBx, a, 0, 0, 0);
          a = __builtin_amdgcn_mfma_f32_16x16x32_bf16(xl, wBx, a, 0, 0, 0);
          a = __builtin_amdgcn_mfma_f32_16x16x32_bf16(xh, wlx, a, 0, 0, 0);
          accB[mt] = a;
        }
      }
#pragma unroll
      for (int mt = 0; mt < 4; ++mt)
#pragma unroll
        for (int v = 0; v < 4; ++v)
          atomicAdd(&zB[(mt * 16 + quad * 4 + v) * 18 + r], accB[mt][v]);
    }

    __syncthreads();

    // ---- gates; stage h into LDS (fragment-contiguous order) ----
    if (tA >= 0 && tA < kT) {
#pragma unroll
      for (int rp = 0; rp < 2; ++rp) {
        int p2 = tid + 512 * rp;
        int b = p2 >> 4, u = p2 & 15;
        float zi = zA[b * 66 + u] + bA[0];
        float zfg = zA[b * 66 + 16 + u] + bA[1];
        float zg = zA[b * 66 + 32 + u] + bA[2];
        float zo = zA[b * 66 + 48 + u] + bA[3];
        float cp = (tA == 0) ? 0.f : (rp ? cA1 : cA0);
        float cn = sigf(zfg) * cp + sigf(zi) * tanh_s(zg);
        float hn = sigf(zo) * tanh_s(cn);
        if (rp) cA1 = cn; else cA0 = cn;
        short hh, ll;
        split_bf16(hn, hh, ll);
        hstA[0][(u >> 3) * 64 + b][u & 7] = (u16)hh;
        hstA[1][(u >> 3) * 64 + b][u & 7] = (u16)ll;
      }
    }
    if (tB < kT && tid < 256) {
      int b = tid >> 2, u2 = tid & 3;
      float zi = zB[b * 18 + u2] + bB[0];
      float zfg = zB[b * 18 + 4 + u2] + bB[1];
      float zg = zB[b * 18 + 8 + u2] + bB[2];
      float zo = zB[b * 18 + 12 + u2] + bB[3];
      float cp = (tB == 0) ? 0.f : cB0;
      float cn = sigf(zfg) * cp + sigf(zi) * tanh_s(zg);
      float hn = sigf(zo) * tanh_s(cn);
      cB0 = cn;
      short hh, ll;
      split_bf16(hn, hh, ll);
      hstB[0][b][u2] = (u16)hh;
      hstB[1][b][u2] = (u16)ll;
    }
    __syncthreads();

    // ---- coalesced write-through h stores (8B/lane, ack at fabric) ----
    if (tA >= 0 && tA < kT) {
      u16* HA = ((wv < 4) ? hhi : hlo) + ((size_t)lA * kT + tA) * BH;
      const int arr = wv >> 2;
      const int ci = (wv & 3) * 64 + lane;
      const int gi = ci >> 1, half = ci & 1;
      u64t v = *(const u64t*)&hstA[arr][gi][half * 4];
      sth8(HA + ((size_t)(jb * 2 + (gi >> 6)) * 64 + (gi & 63)) * 8 + half * 4, v);
    }
    if (tB < kT && wv < 2) {
      u16* HB = (wv ? hlo : hhi) + (size_t)tB * BH;
      u64t v = *(const u64t*)&hstB[wv][lane][0];
      sth8(HB + ((size_t)(ub >> 3) * 64 + lane) * 8 + (ub & 7), v);
    }

    // ---- tree grid barrier: 16 leaves x 16 blocks, monotonic counters ----
    asm volatile("s_waitcnt vmcnt(0) lgkmcnt(0)" ::: "memory");
    __syncthreads();
    if (tid == 0) {
      const int leaf = g >> 4;
      const unsigned tgt = 16u * (unsigned)(s + 1);
      __hip_atomic_fetch_add(&bar[leaf * 32], 1u, __ATOMIC_RELAXED,
                             __HIP_MEMORY_SCOPE_AGENT);
      if ((g & 15) == 0) {
        while (aload(&bar[leaf * 32]) < tgt) __builtin_amdgcn_s_sleep(1);
        __hip_atomic_fetch_add(&bar[512], 1u, __ATOMIC_RELAXED,
                               __HIP_MEMORY_SCOPE_AGENT);
        while (aload(&bar[512]) < tgt) __builtin_amdgcn_s_sleep(2);
        __hip_atomic_store(&bar[544 + leaf * 32], (unsigned)(s + 1),
                           __ATOMIC_RELAXED, __HIP_MEMORY_SCOPE_AGENT);
      } else {
        while (aload(&bar[544 + leaf * 32]) < (unsigned)(s + 1))
          __builtin_amdgcn_s_sleep(4);
      }
    }
    __syncthreads();
    asm volatile("" ::: "memory");
  }

  // ---- head ----
  if (g < 80) {
    int p = g * 8 + wv;
    int b = p / 10, cc = p - b * 10;
    const u16* HH = hhi + ((size_t)kL * kT - 1) * BH;
    const u16* HL = hlo + ((size_t)kL * kT - 1) * BH;
    float sum = 0.f;
    for (int j = lane; j < kH; j += 64) {
      size_t off = ((size_t)(j >> 3) * 64 + b) * 8 + (j & 7);
      sum += (bf2f(HH[off]) + bf2f(HL[off])) * W_head[(size_t)j * kC + cc];
    }
#pragma unroll
    for (int off = 32; off > 0; off >>= 1) sum += __shfl_down(sum, off, 64);
    if (lane == 0) out[p] = sum + b_head[cc];
  }
}

// Fallback buffer (h + int8 wl + barrier counters), allocated at library load.
static char* g_wl = nullptr;
__attribute__((constructor)) static void alloc_wl() {
  hipMalloc((void**)&g_wl,
            2 * H2_ELEMS * sizeof(u16) + WLAQ_BYTES + WLBQ_BYTES + 16384);
}

extern "C" void kernel_launch(void* const* d_in, const int* in_sizes, int n_in,
                              void* d_out, int out_size, void* d_ws, size_t ws_size,
                              hipStream_t stream) {
  const float* x = (const float*)d_in[0];
  const float* Wx0 = (const float*)d_in[1];
  const float* Wxs = (const float*)d_in[2];
  const float* Whs = (const float*)d_in[3];
  const float* bs = (const float*)d_in[4];
  const float* W_head = (const float*)d_in[5];
  const float* b_head = (const float*)d_in[6];
  float* out = (float*)d_out;

  size_t need = 2 * H2_ELEMS * sizeof(u16) + WLAQ_BYTES + WLBQ_BYTES + 16384;
  char* base = (ws_size >= need) ? (char*)d_ws : g_wl;
  u16* hhi = (u16*)base;
  u16* hlo = hhi + H2_ELEMS;
  char* wlAq = (char*)(hlo + H2_ELEMS);
  char* wlBq = wlAq + WLAQ_BYTES;
  unsigned* bar = (unsigned*)(wlBq + WLBQ_BYTES);

  split_wl<<<256, 512, 0, stream>>>(Wx0, Wxs, Whs, wlAq, wlBq, bar);

  void* args[] = {&x, &Wx0, &Wxs, &Whs, &bs, &W_head, &b_head,
                  &out, &hhi, &hlo, &wlAq, &wlBq, &bar};
  hipLaunchCooperativeKernel((void*)lstm_persist, dim3(256), dim3(512), args, 0,
                             stream);
}